// Round 1
// baseline (1119.900 us; speedup 1.0000x reference)
//
#include <hip/hip_runtime.h>

// ---------------- CSR build ----------------

__global__ void k_init(float* deg, int* cnt, int* cursor, int* row_ptr,
                       float* pooled, int N, int pooledN) {
  int i = blockIdx.x * blockDim.x + threadIdx.x;
  if (i < N) { deg[i] = 1.0f; cnt[i] = 0; cursor[i] = 0; }
  if (i < pooledN) pooled[i] = 0.0f;
  if (i == 0) row_ptr[0] = 0;
}

__global__ void k_edge1(const int* __restrict__ ei, const float* __restrict__ ew,
                        float* deg, int* cnt, int E) {
  int stride = gridDim.x * blockDim.x;
  for (int e = blockIdx.x * blockDim.x + threadIdx.x; e < E; e += stride) {
    int dst = ei[E + e];
    atomicAdd(&deg[dst], ew[e]);
    atomicAdd(&cnt[dst], 1);
  }
}

__global__ void k_dinv(float* deg, int N) {
  int i = blockIdx.x * blockDim.x + threadIdx.x;
  if (i < N) deg[i] = rsqrtf(deg[i]);  // deg >= 1 always (self-loop)
}

__global__ void k_scan1(const int* __restrict__ cnt, int* row_ptr, int* bsum, int N) {
  __shared__ int s[1024];
  int t = threadIdx.x;
  int i = blockIdx.x * 1024 + t;
  s[t] = (i < N) ? cnt[i] : 0;
  __syncthreads();
  for (int d = 1; d < 1024; d <<= 1) {
    int add = (t >= d) ? s[t - d] : 0;
    __syncthreads();
    s[t] += add;
    __syncthreads();
  }
  if (i < N) row_ptr[i + 1] = s[t];
  if (t == 1023) bsum[blockIdx.x] = s[1023];
}

__global__ void k_scan2(int* bsum, int nb) {
  if (threadIdx.x == 0 && blockIdx.x == 0) {
    int off = 0;
    for (int j = 0; j < nb; ++j) { int t = bsum[j]; bsum[j] = off; off += t; }
  }
}

__global__ void k_scan3(int* row_ptr, const int* __restrict__ bsum, int N) {
  int i = blockIdx.x * blockDim.x + threadIdx.x;
  if (i < N) {
    int b = i >> 10;
    if (b > 0) row_ptr[i + 1] += bsum[b];
  }
}

__global__ void k_edge2(const int* __restrict__ ei, const float* __restrict__ ew,
                        const float* __restrict__ dinv, const int* __restrict__ row_ptr,
                        int* cursor, int* csr_src, float* csr_norm, int E) {
  int stride = gridDim.x * blockDim.x;
  for (int e = blockIdx.x * blockDim.x + threadIdx.x; e < E; e += stride) {
    int src = ei[e];
    int dst = ei[E + e];
    int pos = row_ptr[dst] + atomicAdd(&cursor[dst], 1);
    csr_src[pos] = src;
    csr_norm[pos] = dinv[src] * ew[e] * dinv[dst];
  }
}

// ---------------- GEMM: C[N,128] = A[N,128] @ W[128,128] (fp32) ----------------

__global__ __launch_bounds__(256) void k_gemm(const float* __restrict__ A,
                                              const float* __restrict__ W,
                                              float* __restrict__ C, int N) {
  __shared__ float As[16][132];  // +4 pad breaks bank-conflict strides
  __shared__ float Ws[16][132];
  int tid = threadIdx.x;
  int row0 = blockIdx.x * 128;
  int cx = tid & 15, cy = tid >> 4;  // cols cx*8.., rows cy*8..
  float acc[8][8];
#pragma unroll
  for (int r = 0; r < 8; ++r)
#pragma unroll
    for (int c = 0; c < 8; ++c) acc[r][c] = 0.f;

  for (int k0 = 0; k0 < 128; k0 += 16) {
    // stage A chunk transposed: As[kk][m] = A[row0+m][k0+kk]
    {
      int kk = tid & 15;
      int mb = (tid >> 4) * 8;
#pragma unroll
      for (int j = 0; j < 8; ++j) {
        int r = row0 + mb + j;
        As[kk][mb + j] = (r < N) ? A[(size_t)r * 128 + k0 + kk] : 0.f;
      }
    }
    // stage W chunk: Ws[kk][n] = W[k0+kk][n]
    {
      int kw = tid >> 4;
      int n0 = (tid & 15) * 8;
      const float* wsrc = &W[(size_t)(k0 + kw) * 128 + n0];
      float4 w0 = *(const float4*)wsrc;
      float4 w1 = *(const float4*)(wsrc + 4);
      *(float4*)&Ws[kw][n0] = w0;
      *(float4*)&Ws[kw][n0 + 4] = w1;
    }
    __syncthreads();
#pragma unroll
    for (int kk = 0; kk < 16; ++kk) {
      float4 a0 = *(float4*)&As[kk][cy * 8];
      float4 a1 = *(float4*)&As[kk][cy * 8 + 4];
      float4 w0 = *(float4*)&Ws[kk][cx * 8];
      float4 w1 = *(float4*)&Ws[kk][cx * 8 + 4];
      float a[8] = {a0.x, a0.y, a0.z, a0.w, a1.x, a1.y, a1.z, a1.w};
      float w[8] = {w0.x, w0.y, w0.z, w0.w, w1.x, w1.y, w1.z, w1.w};
#pragma unroll
      for (int r = 0; r < 8; ++r)
#pragma unroll
        for (int c = 0; c < 8; ++c) acc[r][c] = fmaf(a[r], w[c], acc[r][c]);
    }
    __syncthreads();
  }
#pragma unroll
  for (int r = 0; r < 8; ++r) {
    int rr = row0 + cy * 8 + r;
    if (rr < N) {
      float4 o0 = {acc[r][0], acc[r][1], acc[r][2], acc[r][3]};
      float4 o1 = {acc[r][4], acc[r][5], acc[r][6], acc[r][7]};
      *(float4*)&C[(size_t)rr * 128 + cx * 8] = o0;
      *(float4*)&C[(size_t)rr * 128 + cx * 8 + 4] = o1;
    }
  }
}

// ---------------- Aggregation: out = relu(Ahat @ xw + b) ----------------
// one block (128 threads, feature = tid) per node

__global__ void k_agg(const float* __restrict__ xw, const float* __restrict__ dinv,
                      const int* __restrict__ row_ptr, const int* __restrict__ csr_src,
                      const float* __restrict__ csr_norm, const float* __restrict__ bias,
                      float* __restrict__ out, int N) {
  int node = blockIdx.x;
  if (node >= N) return;
  int f = threadIdx.x;
  float di = dinv[node];
  float acc = di * di * xw[(size_t)node * 128 + f];  // self-loop term
  int s = row_ptr[node], e = row_ptr[node + 1];
  for (int i = s; i < e; ++i) {
    acc += csr_norm[i] * xw[(size_t)csr_src[i] * 128 + f];
  }
  acc += bias[f];
  out[(size_t)node * 128 + f] = fmaxf(acc, 0.f);
}

// ---------------- Pooling (batch_vec sorted -> run-length partials) ----------------

__global__ void k_pool(const float* __restrict__ x, const int* __restrict__ batch,
                       float* pooled, int N) {
  int f = threadIdx.x;          // 128 threads = feature dim
  int n0 = blockIdx.x * 512;
  if (n0 >= N) return;
  int n1 = min(n0 + 512, N);
  int cur = batch[n0];
  float acc = 0.f;
  for (int n = n0; n < n1; ++n) {
    int b = batch[n];
    if (b != cur) {
      atomicAdd(&pooled[cur * 128 + f], acc);
      acc = 0.f;
      cur = b;
    }
    acc += x[(size_t)n * 128 + f];
  }
  atomicAdd(&pooled[cur * 128 + f], acc);
}

__global__ void k_final(const float* __restrict__ pooled, const float* __restrict__ lw,
                        const float* __restrict__ lb, float* __restrict__ out) {
  int b = blockIdx.x;
  int l = threadIdx.x;  // 64
  float s = pooled[b * 128 + l] * lw[l] + pooled[b * 128 + 64 + l] * lw[64 + l];
#pragma unroll
  for (int o = 32; o > 0; o >>= 1) s += __shfl_down(s, o, 64);
  if (l == 0) out[b] = s + lb[0];
}

// ---------------- host ----------------

extern "C" void kernel_launch(void* const* d_in, const int* in_sizes, int n_in,
                              void* d_out, int out_size, void* d_ws, size_t ws_size,
                              hipStream_t stream) {
  const float* X  = (const float*)d_in[0];
  const int*   ei = (const int*)d_in[1];
  const float* ew = (const float*)d_in[2];
  const int*   bv = (const int*)d_in[3];
  const float* W1 = (const float*)d_in[4];
  const float* b1 = (const float*)d_in[5];
  const float* W2 = (const float*)d_in[6];
  const float* b2 = (const float*)d_in[7];
  const float* W3 = (const float*)d_in[8];
  const float* b3 = (const float*)d_in[9];
  const float* lw = (const float*)d_in[10];
  const float* lb = (const float*)d_in[11];
  float* out = (float*)d_out;

  int N = in_sizes[0] / 128;
  int E = in_sizes[2];
  int B = out_size;

  char* wsp = (char*)d_ws;
  size_t off = 0;
  auto alloc = [&](size_t bytes) -> void* {
    void* p = wsp + off;
    off += (bytes + 255) & ~(size_t)255;
    return p;
  };
  float* deg      = (float*)alloc((size_t)N * 4);  // becomes dinv in place
  int*   cnt      = (int*)alloc((size_t)N * 4);
  int*   cursor   = (int*)alloc((size_t)N * 4);
  int*   row_ptr  = (int*)alloc((size_t)(N + 1) * 4);
  int*   bsum     = (int*)alloc(256 * 4);
  int*   csr_src  = (int*)alloc((size_t)E * 4);
  float* csr_norm = (float*)alloc((size_t)E * 4);
  float* buf0     = (float*)alloc((size_t)N * 128 * 4);  // xw scratch
  float* buf1     = (float*)alloc((size_t)N * 128 * 4);  // h scratch
  float* pooled   = (float*)alloc((size_t)B * 128 * 4);
  (void)ws_size; (void)n_in;

  int nthr = 256;
  int nb_n = (N + nthr - 1) / nthr;
  int nb1 = (N + 1023) / 1024;

  k_init<<<nb_n, nthr, 0, stream>>>(deg, cnt, cursor, row_ptr, pooled, N, B * 128);
  k_edge1<<<2048, 256, 0, stream>>>(ei, ew, deg, cnt, E);
  k_dinv<<<nb_n, nthr, 0, stream>>>(deg, N);
  k_scan1<<<nb1, 1024, 0, stream>>>(cnt, row_ptr, bsum, N);
  k_scan2<<<1, 64, 0, stream>>>(bsum, nb1);
  k_scan3<<<nb_n, nthr, 0, stream>>>(row_ptr, bsum, N);
  k_edge2<<<2048, 256, 0, stream>>>(ei, ew, deg, row_ptr, cursor, csr_src, csr_norm, E);

  int gblocks = (N + 127) / 128;
  // layer 1
  k_gemm<<<gblocks, 256, 0, stream>>>(X, W1, buf0, N);
  k_agg<<<N, 128, 0, stream>>>(buf0, deg, row_ptr, csr_src, csr_norm, b1, buf1, N);
  // layer 2
  k_gemm<<<gblocks, 256, 0, stream>>>(buf1, W2, buf0, N);
  k_agg<<<N, 128, 0, stream>>>(buf0, deg, row_ptr, csr_src, csr_norm, b2, buf1, N);
  // layer 3
  k_gemm<<<gblocks, 256, 0, stream>>>(buf1, W3, buf0, N);
  k_agg<<<N, 128, 0, stream>>>(buf0, deg, row_ptr, csr_src, csr_norm, b3, buf1, N);

  int pblocks = (N + 511) / 512;
  k_pool<<<pblocks, 128, 0, stream>>>(buf1, bv, pooled, N);
  k_final<<<B, 64, 0, stream>>>(pooled, lw, lb, out);
}

// Round 2
// 720.560 us; speedup vs baseline: 1.5542x; 1.5542x over previous
//
#include <hip/hip_runtime.h>

typedef __attribute__((ext_vector_type(8))) short bf16x8;
typedef __attribute__((ext_vector_type(4))) float f32x4;

__device__ __forceinline__ ushort f2bf(float f) {
  union { float f; uint u; } v; v.f = f;
  uint r = (v.u + 0x7fffu + ((v.u >> 16) & 1u)) >> 16;
  return (ushort)r;
}
__device__ __forceinline__ float2 bfp2f(uint p) {  // packed 2x bf16 -> 2x f32
  union { uint u; float f; } lo, hi;
  lo.u = p << 16; hi.u = p & 0xffff0000u;
  float2 r; r.x = lo.f; r.y = hi.f; return r;
}

// ---------------- CSR build ----------------

__global__ void k_init(float* deg, int* cnt, int* cursor, int* row_ptr,
                       float* pooled, int N, int pooledN) {
  int i = blockIdx.x * blockDim.x + threadIdx.x;
  if (i < N) { deg[i] = 1.0f; cnt[i] = 0; cursor[i] = 0; }
  if (i < pooledN) pooled[i] = 0.0f;
  if (i == 0) row_ptr[0] = 0;
}

__global__ void k_edge1(const int* __restrict__ ei, const float* __restrict__ ew,
                        float* deg, int* cnt, int E) {
  int stride = gridDim.x * blockDim.x;
  for (int e = blockIdx.x * blockDim.x + threadIdx.x; e < E; e += stride) {
    int dst = ei[E + e];
    atomicAdd(&deg[dst], ew[e]);
    atomicAdd(&cnt[dst], 1);
  }
}

__global__ void k_dinv(float* deg, int N) {
  int i = blockIdx.x * blockDim.x + threadIdx.x;
  if (i < N) deg[i] = rsqrtf(deg[i]);  // deg >= 1 always (self-loop)
}

__global__ void k_scan1(const int* __restrict__ cnt, int* row_ptr, int* bsum, int N) {
  __shared__ int s[1024];
  int t = threadIdx.x;
  int i = blockIdx.x * 1024 + t;
  s[t] = (i < N) ? cnt[i] : 0;
  __syncthreads();
  for (int d = 1; d < 1024; d <<= 1) {
    int add = (t >= d) ? s[t - d] : 0;
    __syncthreads();
    s[t] += add;
    __syncthreads();
  }
  if (i < N) row_ptr[i + 1] = s[t];
  if (t == 1023) bsum[blockIdx.x] = s[1023];
}

__global__ void k_scan2(int* bsum, int nb) {
  if (threadIdx.x == 0 && blockIdx.x == 0) {
    int off = 0;
    for (int j = 0; j < nb; ++j) { int t = bsum[j]; bsum[j] = off; off += t; }
  }
}

__global__ void k_scan3(int* row_ptr, const int* __restrict__ bsum, int N) {
  int i = blockIdx.x * blockDim.x + threadIdx.x;
  if (i < N) {
    int b = i >> 10;
    if (b > 0) row_ptr[i + 1] += bsum[b];
  }
}

__global__ void k_edge2(const int* __restrict__ ei, const float* __restrict__ ew,
                        const float* __restrict__ dinv, const int* __restrict__ row_ptr,
                        int* cursor, int* csr_src, float* csr_norm, int E) {
  int stride = gridDim.x * blockDim.x;
  for (int e = blockIdx.x * blockDim.x + threadIdx.x; e < E; e += stride) {
    int src = ei[e];
    int dst = ei[E + e];
    int pos = row_ptr[dst] + atomicAdd(&cursor[dst], 1);
    csr_src[pos] = src;
    csr_norm[pos] = dinv[src] * ew[e] * dinv[dst];
  }
}

// ---------------- weight transpose + cast: Wt[c][k] = bf16(W[k][c]) ----------------

__global__ void k_wt3(const float* __restrict__ W1, const float* __restrict__ W2,
                      const float* __restrict__ W3, ushort* T1, ushort* T2, ushort* T3) {
  int which = blockIdx.x >> 6;
  const float* W = which == 0 ? W1 : (which == 1 ? W2 : W3);
  ushort* T = which == 0 ? T1 : (which == 1 ? T2 : T3);
  int idx = (blockIdx.x & 63) * 256 + threadIdx.x;  // 64 blocks * 256 = 16384
  int k = idx >> 7, c = idx & 127;
  T[c * 128 + k] = f2bf(W[idx]);
}

// ---------------- MFMA GEMM: C[N,128](bf16) = A[N,128] @ W[128,128] ----------------
// Wt is W transposed, bf16. A is fp32 (AF32=1) or bf16 (AF32=0).
// Per wave: 16 rows, 8 col-tiles of 16, K=128 in 4 chunks of 32.

template<int AF32>
__global__ __launch_bounds__(256) void k_gemm(const void* __restrict__ Ap,
                                              const ushort* __restrict__ Wt,
                                              ushort* __restrict__ C, int N) {
  int wid = threadIdx.x >> 6, lane = threadIdx.x & 63;
  int row0 = blockIdx.x * 64 + wid * 16;
  int r = lane & 15, kh = lane >> 4;  // A/B frag: row/col = r, k = kh*8 + j
  int arow = row0 + r;
  bool inb = arow < N;
  bf16x8 afrag[4];
#pragma unroll
  for (int kc = 0; kc < 4; ++kc) {
    if (inb) {
      if constexpr (AF32) {
        const float* A = (const float*)Ap;
        const float* p = &A[(size_t)arow * 128 + kc * 32 + kh * 8];
        float4 x0 = *(const float4*)p;
        float4 x1 = *(const float4*)(p + 4);
        bf16x8 t;
        t[0] = (short)f2bf(x0.x); t[1] = (short)f2bf(x0.y);
        t[2] = (short)f2bf(x0.z); t[3] = (short)f2bf(x0.w);
        t[4] = (short)f2bf(x1.x); t[5] = (short)f2bf(x1.y);
        t[6] = (short)f2bf(x1.z); t[7] = (short)f2bf(x1.w);
        afrag[kc] = t;
      } else {
        const ushort* A = (const ushort*)Ap;
        afrag[kc] = *(const bf16x8*)&A[(size_t)arow * 128 + kc * 32 + kh * 8];
      }
    } else {
      bf16x8 z = {0, 0, 0, 0, 0, 0, 0, 0};
      afrag[kc] = z;
    }
  }
  f32x4 acc[8];
#pragma unroll
  for (int ct = 0; ct < 8; ++ct) { f32x4 z = {0.f, 0.f, 0.f, 0.f}; acc[ct] = z; }
#pragma unroll
  for (int ct = 0; ct < 8; ++ct) {
#pragma unroll
    for (int kc = 0; kc < 4; ++kc) {
      bf16x8 b = *(const bf16x8*)&Wt[(size_t)(ct * 16 + r) * 128 + kc * 32 + kh * 8];
      acc[ct] = __builtin_amdgcn_mfma_f32_16x16x32_bf16(afrag[kc], b, acc[ct], 0, 0, 0);
    }
  }
  // C/D layout: col = lane&15 (=r), row-in-tile = kh*4 + rr
#pragma unroll
  for (int ct = 0; ct < 8; ++ct) {
#pragma unroll
    for (int rr = 0; rr < 4; ++rr) {
      int row = row0 + kh * 4 + rr;
      if (row < N) C[(size_t)row * 128 + ct * 16 + r] = f2bf(acc[ct][rr]);
    }
  }
}

// ---------------- Aggregation: out = relu(Ahat @ xw + b), bf16 in/out ----------------
// one wave per node; lane l owns features 2l, 2l+1 (one packed uint per row)

__global__ __launch_bounds__(256) void k_agg(const ushort* __restrict__ xw,
                                             const float* __restrict__ dinv,
                                             const int* __restrict__ row_ptr,
                                             const int* __restrict__ csr_src,
                                             const float* __restrict__ csr_norm,
                                             const float* __restrict__ bias,
                                             ushort* __restrict__ out, int N) {
  int wid = threadIdx.x >> 6, lane = threadIdx.x & 63;
  int node = blockIdx.x * 4 + wid;
  if (node >= N) return;
  float di = dinv[node];
  uint selfp = *(const uint*)&xw[(size_t)node * 128 + lane * 2];
  float2 sv = bfp2f(selfp);
  float w0 = di * di;
  float2 a0 = {sv.x * w0, sv.y * w0};
  float2 a1 = {0.f, 0.f}, a2 = {0.f, 0.f}, a3 = {0.f, 0.f};
  int s = row_ptr[node], e = row_ptr[node + 1];
  int i = s;
  for (; i + 4 <= e; i += 4) {
    int s0 = csr_src[i], s1 = csr_src[i + 1], s2 = csr_src[i + 2], s3 = csr_src[i + 3];
    float n0 = csr_norm[i], n1 = csr_norm[i + 1], n2 = csr_norm[i + 2], n3 = csr_norm[i + 3];
    uint g0 = *(const uint*)&xw[(size_t)s0 * 128 + lane * 2];
    uint g1 = *(const uint*)&xw[(size_t)s1 * 128 + lane * 2];
    uint g2 = *(const uint*)&xw[(size_t)s2 * 128 + lane * 2];
    uint g3 = *(const uint*)&xw[(size_t)s3 * 128 + lane * 2];
    float2 f0 = bfp2f(g0), f1 = bfp2f(g1), f2 = bfp2f(g2), f3 = bfp2f(g3);
    a0.x = fmaf(n0, f0.x, a0.x); a0.y = fmaf(n0, f0.y, a0.y);
    a1.x = fmaf(n1, f1.x, a1.x); a1.y = fmaf(n1, f1.y, a1.y);
    a2.x = fmaf(n2, f2.x, a2.x); a2.y = fmaf(n2, f2.y, a2.y);
    a3.x = fmaf(n3, f3.x, a3.x); a3.y = fmaf(n3, f3.y, a3.y);
  }
  for (; i < e; ++i) {
    int s0 = csr_src[i]; float n0 = csr_norm[i];
    uint g0 = *(const uint*)&xw[(size_t)s0 * 128 + lane * 2];
    float2 f0 = bfp2f(g0);
    a0.x = fmaf(n0, f0.x, a0.x); a0.y = fmaf(n0, f0.y, a0.y);
  }
  float bx = bias[lane * 2], by = bias[lane * 2 + 1];
  float rx = fmaxf(a0.x + a1.x + a2.x + a3.x + bx, 0.f);
  float ry = fmaxf(a0.y + a1.y + a2.y + a3.y + by, 0.f);
  ushort2 o = {f2bf(rx), f2bf(ry)};
  *(ushort2*)&out[(size_t)node * 128 + lane * 2] = o;
}

// ---------------- Pooling (batch_vec sorted -> run-length partials) ----------------

__global__ void k_pool(const ushort* __restrict__ x, const int* __restrict__ batch,
                       float* pooled, int N) {
  int f = threadIdx.x;  // 128 threads = feature dim
  int n0 = blockIdx.x * 512;
  if (n0 >= N) return;
  int n1 = min(n0 + 512, N);
  int cur = batch[n0];
  float acc = 0.f;
  for (int n = n0; n < n1; ++n) {
    int b = batch[n];
    if (b != cur) {
      atomicAdd(&pooled[cur * 128 + f], acc);
      acc = 0.f;
      cur = b;
    }
    union { uint u; float fl; } v; v.u = ((uint)x[(size_t)n * 128 + f]) << 16;
    acc += v.fl;
  }
  atomicAdd(&pooled[cur * 128 + f], acc);
}

__global__ void k_final(const float* __restrict__ pooled, const float* __restrict__ lw,
                        const float* __restrict__ lb, float* __restrict__ out) {
  int b = blockIdx.x;
  int l = threadIdx.x;  // 64
  float s = pooled[b * 128 + l] * lw[l] + pooled[b * 128 + 64 + l] * lw[64 + l];
#pragma unroll
  for (int o = 32; o > 0; o >>= 1) s += __shfl_down(s, o, 64);
  if (l == 0) out[b] = s + lb[0];
}

// ---------------- host ----------------

extern "C" void kernel_launch(void* const* d_in, const int* in_sizes, int n_in,
                              void* d_out, int out_size, void* d_ws, size_t ws_size,
                              hipStream_t stream) {
  const float* X  = (const float*)d_in[0];
  const int*   ei = (const int*)d_in[1];
  const float* ew = (const float*)d_in[2];
  const int*   bv = (const int*)d_in[3];
  const float* W1 = (const float*)d_in[4];
  const float* b1 = (const float*)d_in[5];
  const float* W2 = (const float*)d_in[6];
  const float* b2 = (const float*)d_in[7];
  const float* W3 = (const float*)d_in[8];
  const float* b3 = (const float*)d_in[9];
  const float* lw = (const float*)d_in[10];
  const float* lb = (const float*)d_in[11];
  float* out = (float*)d_out;

  int N = in_sizes[0] / 128;
  int E = in_sizes[2];
  int B = out_size;

  char* wsp = (char*)d_ws;
  size_t off = 0;
  auto alloc = [&](size_t bytes) -> void* {
    void* p = wsp + off;
    off += (bytes + 255) & ~(size_t)255;
    return p;
  };
  float*  deg      = (float*)alloc((size_t)N * 4);  // becomes dinv in place
  int*    cnt      = (int*)alloc((size_t)N * 4);
  int*    cursor   = (int*)alloc((size_t)N * 4);
  int*    row_ptr  = (int*)alloc((size_t)(N + 1) * 4);
  int*    bsum     = (int*)alloc(256 * 4);
  int*    csr_src  = (int*)alloc((size_t)E * 4);
  float*  csr_norm = (float*)alloc((size_t)E * 4);
  ushort* wt1      = (ushort*)alloc(128 * 128 * 2);
  ushort* wt2      = (ushort*)alloc(128 * 128 * 2);
  ushort* wt3      = (ushort*)alloc(128 * 128 * 2);
  ushort* buf0     = (ushort*)alloc((size_t)N * 128 * 2);  // xw scratch (bf16)
  ushort* buf1     = (ushort*)alloc((size_t)N * 128 * 2);  // h scratch (bf16)
  float*  pooled   = (float*)alloc((size_t)B * 128 * 4);
  (void)ws_size; (void)n_in;

  int nthr = 256;
  int nb_n = (N + nthr - 1) / nthr;
  int nb1 = (N + 1023) / 1024;

  k_init<<<nb_n, nthr, 0, stream>>>(deg, cnt, cursor, row_ptr, pooled, N, B * 128);
  k_edge1<<<2048, 256, 0, stream>>>(ei, ew, deg, cnt, E);
  k_dinv<<<nb_n, nthr, 0, stream>>>(deg, N);
  k_scan1<<<nb1, 1024, 0, stream>>>(cnt, row_ptr, bsum, N);
  k_scan2<<<1, 64, 0, stream>>>(bsum, nb1);
  k_scan3<<<nb_n, nthr, 0, stream>>>(row_ptr, bsum, N);
  k_edge2<<<2048, 256, 0, stream>>>(ei, ew, deg, row_ptr, cursor, csr_src, csr_norm, E);
  k_wt3<<<192, 256, 0, stream>>>(W1, W2, W3, wt1, wt2, wt3);

  int gblocks = (N + 63) / 64;
  int ablocks = (N + 3) / 4;
  // layer 1 (A = X fp32)
  k_gemm<1><<<gblocks, 256, 0, stream>>>(X, wt1, buf0, N);
  k_agg<<<ablocks, 256, 0, stream>>>(buf0, deg, row_ptr, csr_src, csr_norm, b1, buf1, N);
  // layer 2
  k_gemm<0><<<gblocks, 256, 0, stream>>>(buf1, wt2, buf0, N);
  k_agg<<<ablocks, 256, 0, stream>>>(buf0, deg, row_ptr, csr_src, csr_norm, b2, buf1, N);
  // layer 3
  k_gemm<0><<<gblocks, 256, 0, stream>>>(buf1, wt3, buf0, N);
  k_agg<<<ablocks, 256, 0, stream>>>(buf0, deg, row_ptr, csr_src, csr_norm, b3, buf1, N);

  int pblocks = (N + 511) / 512;
  k_pool<<<pblocks, 128, 0, stream>>>(buf1, bv, pooled, N);
  k_final<<<B, 64, 0, stream>>>(pooled, lw, lb, out);
}

// Round 3
// 599.046 us; speedup vs baseline: 1.8695x; 1.2028x over previous
//
#include <hip/hip_runtime.h>

typedef __attribute__((ext_vector_type(8))) short bf16x8;
typedef __attribute__((ext_vector_type(4))) float f32x4;

__device__ __forceinline__ ushort f2bf(float f) {
  union { float f; uint u; } v; v.f = f;
  uint r = (v.u + 0x7fffu + ((v.u >> 16) & 1u)) >> 16;
  return (ushort)r;
}
__device__ __forceinline__ float2 bfp2f(uint p) {  // packed 2x bf16 -> 2x f32
  union { uint u; float f; } lo, hi;
  lo.u = p << 16; hi.u = p & 0xffff0000u;
  float2 r; r.x = lo.f; r.y = hi.f; return r;
}

// ---------------- CSR build ----------------

__global__ void k_init(float* deg, int* cnt, int* cursor, int* row_ptr,
                       float* pooled, int N, int pooledN) {
  int i = blockIdx.x * blockDim.x + threadIdx.x;
  if (i < N) { deg[i] = 1.0f; cnt[i] = 0; cursor[i] = 0; }
  if (i < pooledN) pooled[i] = 0.0f;
  if (i == 0) row_ptr[0] = 0;
}

__global__ void k_edge1(const int* __restrict__ ei, const float* __restrict__ ew,
                        float* deg, int* cnt, int E) {
  int stride = gridDim.x * blockDim.x;
  for (int e = blockIdx.x * blockDim.x + threadIdx.x; e < E; e += stride) {
    int dst = ei[E + e];
    atomicAdd(&deg[dst], ew[e]);
    atomicAdd(&cnt[dst], 1);
  }
}

__global__ void k_dinv(float* deg, int N) {
  int i = blockIdx.x * blockDim.x + threadIdx.x;
  if (i < N) deg[i] = rsqrtf(deg[i]);  // deg >= 1 always (self-loop)
}

__global__ void k_scan1(const int* __restrict__ cnt, int* row_ptr, int* bsum, int N) {
  __shared__ int s[1024];
  int t = threadIdx.x;
  int i = blockIdx.x * 1024 + t;
  s[t] = (i < N) ? cnt[i] : 0;
  __syncthreads();
  for (int d = 1; d < 1024; d <<= 1) {
    int add = (t >= d) ? s[t - d] : 0;
    __syncthreads();
    s[t] += add;
    __syncthreads();
  }
  if (i < N) row_ptr[i + 1] = s[t];
  if (t == 1023) bsum[blockIdx.x] = s[1023];
}

__global__ void k_scan2(int* bsum, int nb) {
  if (threadIdx.x == 0 && blockIdx.x == 0) {
    int off = 0;
    for (int j = 0; j < nb; ++j) { int t = bsum[j]; bsum[j] = off; off += t; }
  }
}

__global__ void k_scan3(int* row_ptr, const int* __restrict__ bsum, int N) {
  int i = blockIdx.x * blockDim.x + threadIdx.x;
  if (i < N) {
    int b = i >> 10;
    if (b > 0) row_ptr[i + 1] += bsum[b];
  }
}

__global__ void k_edge2(const int* __restrict__ ei, const float* __restrict__ ew,
                        const float* __restrict__ dinv, const int* __restrict__ row_ptr,
                        int* cursor, int* csr_src, float* csr_norm, int E) {
  int stride = gridDim.x * blockDim.x;
  for (int e = blockIdx.x * blockDim.x + threadIdx.x; e < E; e += stride) {
    int src = ei[e];
    int dst = ei[E + e];
    int pos = row_ptr[dst] + atomicAdd(&cursor[dst], 1);
    csr_src[pos] = src;
    csr_norm[pos] = dinv[src] * ew[e] * dinv[dst];
  }
}

// ---------------- weight transpose + cast: Wt[c][k] = bf16(W[k][c]) ----------------

__global__ void k_wt3(const float* __restrict__ W1, const float* __restrict__ W2,
                      const float* __restrict__ W3, ushort* T1, ushort* T2, ushort* T3) {
  int which = blockIdx.x >> 6;
  const float* W = which == 0 ? W1 : (which == 1 ? W2 : W3);
  ushort* T = which == 0 ? T1 : (which == 1 ? T2 : T3);
  int idx = (blockIdx.x & 63) * 256 + threadIdx.x;  // 64 blocks * 256 = 16384
  int k = idx >> 7, c = idx & 127;
  T[c * 128 + k] = f2bf(W[idx]);
}

// ---------------- MFMA GEMM: C[N,128](bf16) = A[N,128] @ W[128,128] ----------------
// Wt is W transposed, bf16. A is fp32 (AF32=1) or bf16 (AF32=0).
// Per wave: 16 rows, 8 col-tiles of 16, K=128 in 4 chunks of 32.

template<int AF32>
__global__ __launch_bounds__(256) void k_gemm(const void* __restrict__ Ap,
                                              const ushort* __restrict__ Wt,
                                              ushort* __restrict__ C, int N) {
  int wid = threadIdx.x >> 6, lane = threadIdx.x & 63;
  int row0 = blockIdx.x * 64 + wid * 16;
  int r = lane & 15, kh = lane >> 4;  // A/B frag: row/col = r, k = kh*8 + j
  int arow = row0 + r;
  bool inb = arow < N;
  bf16x8 afrag[4];
#pragma unroll
  for (int kc = 0; kc < 4; ++kc) {
    if (inb) {
      if constexpr (AF32) {
        const float* A = (const float*)Ap;
        const float* p = &A[(size_t)arow * 128 + kc * 32 + kh * 8];
        float4 x0 = *(const float4*)p;
        float4 x1 = *(const float4*)(p + 4);
        bf16x8 t;
        t[0] = (short)f2bf(x0.x); t[1] = (short)f2bf(x0.y);
        t[2] = (short)f2bf(x0.z); t[3] = (short)f2bf(x0.w);
        t[4] = (short)f2bf(x1.x); t[5] = (short)f2bf(x1.y);
        t[6] = (short)f2bf(x1.z); t[7] = (short)f2bf(x1.w);
        afrag[kc] = t;
      } else {
        const ushort* A = (const ushort*)Ap;
        afrag[kc] = *(const bf16x8*)&A[(size_t)arow * 128 + kc * 32 + kh * 8];
      }
    } else {
      bf16x8 z = {0, 0, 0, 0, 0, 0, 0, 0};
      afrag[kc] = z;
    }
  }
  f32x4 acc[8];
#pragma unroll
  for (int ct = 0; ct < 8; ++ct) { f32x4 z = {0.f, 0.f, 0.f, 0.f}; acc[ct] = z; }
#pragma unroll
  for (int ct = 0; ct < 8; ++ct) {
#pragma unroll
    for (int kc = 0; kc < 4; ++kc) {
      bf16x8 b = *(const bf16x8*)&Wt[(size_t)(ct * 16 + r) * 128 + kc * 32 + kh * 8];
      acc[ct] = __builtin_amdgcn_mfma_f32_16x16x32_bf16(afrag[kc], b, acc[ct], 0, 0, 0);
    }
  }
  // C/D layout: col = lane&15 (=r), row-in-tile = kh*4 + rr
#pragma unroll
  for (int ct = 0; ct < 8; ++ct) {
#pragma unroll
    for (int rr = 0; rr < 4; ++rr) {
      int row = row0 + kh * 4 + rr;
      if (row < N) C[(size_t)row * 128 + ct * 16 + r] = f2bf(acc[ct][rr]);
    }
  }
}

// ---------------- Aggregation: out = relu(Ahat @ xw + b), bf16 in/out ----------------
// one wave per node; lane l owns features 2l, 2l+1 (one packed uint per row)

__global__ __launch_bounds__(256) void k_agg(const ushort* __restrict__ xw,
                                             const float* __restrict__ dinv,
                                             const int* __restrict__ row_ptr,
                                             const int* __restrict__ csr_src,
                                             const float* __restrict__ csr_norm,
                                             const float* __restrict__ bias,
                                             ushort* __restrict__ out, int N) {
  int wid = threadIdx.x >> 6, lane = threadIdx.x & 63;
  int node = blockIdx.x * 4 + wid;
  if (node >= N) return;
  float di = dinv[node];
  uint selfp = *(const uint*)&xw[(size_t)node * 128 + lane * 2];
  float2 sv = bfp2f(selfp);
  float w0 = di * di;
  float2 a0 = {sv.x * w0, sv.y * w0};
  float2 a1 = {0.f, 0.f}, a2 = {0.f, 0.f}, a3 = {0.f, 0.f};
  int s = row_ptr[node], e = row_ptr[node + 1];
  int i = s;
  for (; i + 4 <= e; i += 4) {
    int s0 = csr_src[i], s1 = csr_src[i + 1], s2 = csr_src[i + 2], s3 = csr_src[i + 3];
    float n0 = csr_norm[i], n1 = csr_norm[i + 1], n2 = csr_norm[i + 2], n3 = csr_norm[i + 3];
    uint g0 = *(const uint*)&xw[(size_t)s0 * 128 + lane * 2];
    uint g1 = *(const uint*)&xw[(size_t)s1 * 128 + lane * 2];
    uint g2 = *(const uint*)&xw[(size_t)s2 * 128 + lane * 2];
    uint g3 = *(const uint*)&xw[(size_t)s3 * 128 + lane * 2];
    float2 f0 = bfp2f(g0), f1 = bfp2f(g1), f2 = bfp2f(g2), f3 = bfp2f(g3);
    a0.x = fmaf(n0, f0.x, a0.x); a0.y = fmaf(n0, f0.y, a0.y);
    a1.x = fmaf(n1, f1.x, a1.x); a1.y = fmaf(n1, f1.y, a1.y);
    a2.x = fmaf(n2, f2.x, a2.x); a2.y = fmaf(n2, f2.y, a2.y);
    a3.x = fmaf(n3, f3.x, a3.x); a3.y = fmaf(n3, f3.y, a3.y);
  }
  for (; i < e; ++i) {
    int s0 = csr_src[i]; float n0 = csr_norm[i];
    uint g0 = *(const uint*)&xw[(size_t)s0 * 128 + lane * 2];
    float2 f0 = bfp2f(g0);
    a0.x = fmaf(n0, f0.x, a0.x); a0.y = fmaf(n0, f0.y, a0.y);
  }
  float bx = bias[lane * 2], by = bias[lane * 2 + 1];
  float rx = fmaxf(a0.x + a1.x + a2.x + a3.x + bx, 0.f);
  float ry = fmaxf(a0.y + a1.y + a2.y + a3.y + by, 0.f);
  ushort2 o = {f2bf(rx), f2bf(ry)};
  *(ushort2*)&out[(size_t)node * 128 + lane * 2] = o;
}

// ---------------- Pooling: one wave per 32-node chunk, lane owns 2 features ----------------
// batch_vec is sorted, so run-length accumulate within the chunk and flush on
// boundary. The b!=cur branch is wave-uniform (batch[n] identical across lanes).

__global__ __launch_bounds__(256) void k_pool(const ushort* __restrict__ x,
                                              const int* __restrict__ batch,
                                              float* pooled, int N) {
  int wid = threadIdx.x >> 6, lane = threadIdx.x & 63;
  int n0 = (blockIdx.x * 4 + wid) * 32;
  if (n0 >= N) return;
  int n1 = min(n0 + 32, N);
  int cur = batch[n0];
  float ax = 0.f, ay = 0.f;
  for (int n = n0; n < n1; ++n) {
    int b = batch[n];
    if (b != cur) {
      atomicAdd(&pooled[cur * 128 + lane * 2], ax);
      atomicAdd(&pooled[cur * 128 + lane * 2 + 1], ay);
      ax = 0.f; ay = 0.f;
      cur = b;
    }
    uint p = *(const uint*)&x[(size_t)n * 128 + lane * 2];
    float2 f = bfp2f(p);
    ax += f.x; ay += f.y;
  }
  atomicAdd(&pooled[cur * 128 + lane * 2], ax);
  atomicAdd(&pooled[cur * 128 + lane * 2 + 1], ay);
}

__global__ void k_final(const float* __restrict__ pooled, const float* __restrict__ lw,
                        const float* __restrict__ lb, float* __restrict__ out) {
  int b = blockIdx.x;
  int l = threadIdx.x;  // 64
  float s = pooled[b * 128 + l] * lw[l] + pooled[b * 128 + 64 + l] * lw[64 + l];
#pragma unroll
  for (int o = 32; o > 0; o >>= 1) s += __shfl_down(s, o, 64);
  if (l == 0) out[b] = s + lb[0];
}

// ---------------- host ----------------

extern "C" void kernel_launch(void* const* d_in, const int* in_sizes, int n_in,
                              void* d_out, int out_size, void* d_ws, size_t ws_size,
                              hipStream_t stream) {
  const float* X  = (const float*)d_in[0];
  const int*   ei = (const int*)d_in[1];
  const float* ew = (const float*)d_in[2];
  const int*   bv = (const int*)d_in[3];
  const float* W1 = (const float*)d_in[4];
  const float* b1 = (const float*)d_in[5];
  const float* W2 = (const float*)d_in[6];
  const float* b2 = (const float*)d_in[7];
  const float* W3 = (const float*)d_in[8];
  const float* b3 = (const float*)d_in[9];
  const float* lw = (const float*)d_in[10];
  const float* lb = (const float*)d_in[11];
  float* out = (float*)d_out;

  int N = in_sizes[0] / 128;
  int E = in_sizes[2];
  int B = out_size;

  char* wsp = (char*)d_ws;
  size_t off = 0;
  auto alloc = [&](size_t bytes) -> void* {
    void* p = wsp + off;
    off += (bytes + 255) & ~(size_t)255;
    return p;
  };
  float*  deg      = (float*)alloc((size_t)N * 4);  // becomes dinv in place
  int*    cnt      = (int*)alloc((size_t)N * 4);
  int*    cursor   = (int*)alloc((size_t)N * 4);
  int*    row_ptr  = (int*)alloc((size_t)(N + 1) * 4);
  int*    bsum     = (int*)alloc(256 * 4);
  int*    csr_src  = (int*)alloc((size_t)E * 4);
  float*  csr_norm = (float*)alloc((size_t)E * 4);
  ushort* wt1      = (ushort*)alloc(128 * 128 * 2);
  ushort* wt2      = (ushort*)alloc(128 * 128 * 2);
  ushort* wt3      = (ushort*)alloc(128 * 128 * 2);
  ushort* buf0     = (ushort*)alloc((size_t)N * 128 * 2);  // xw scratch (bf16)
  ushort* buf1     = (ushort*)alloc((size_t)N * 128 * 2);  // h scratch (bf16)
  float*  pooled   = (float*)alloc((size_t)B * 128 * 4);
  (void)ws_size; (void)n_in;

  int nthr = 256;
  int nb_n = (N + nthr - 1) / nthr;
  int nb1 = (N + 1023) / 1024;

  k_init<<<nb_n, nthr, 0, stream>>>(deg, cnt, cursor, row_ptr, pooled, N, B * 128);
  k_edge1<<<2048, 256, 0, stream>>>(ei, ew, deg, cnt, E);
  k_dinv<<<nb_n, nthr, 0, stream>>>(deg, N);
  k_scan1<<<nb1, 1024, 0, stream>>>(cnt, row_ptr, bsum, N);
  k_scan2<<<1, 64, 0, stream>>>(bsum, nb1);
  k_scan3<<<nb_n, nthr, 0, stream>>>(row_ptr, bsum, N);
  k_edge2<<<2048, 256, 0, stream>>>(ei, ew, deg, row_ptr, cursor, csr_src, csr_norm, E);
  k_wt3<<<192, 256, 0, stream>>>(W1, W2, W3, wt1, wt2, wt3);

  int gblocks = (N + 63) / 64;
  int ablocks = (N + 3) / 4;
  // layer 1 (A = X fp32)
  k_gemm<1><<<gblocks, 256, 0, stream>>>(X, wt1, buf0, N);
  k_agg<<<ablocks, 256, 0, stream>>>(buf0, deg, row_ptr, csr_src, csr_norm, b1, buf1, N);
  // layer 2
  k_gemm<0><<<gblocks, 256, 0, stream>>>(buf1, wt2, buf0, N);
  k_agg<<<ablocks, 256, 0, stream>>>(buf0, deg, row_ptr, csr_src, csr_norm, b2, buf1, N);
  // layer 3
  k_gemm<0><<<gblocks, 256, 0, stream>>>(buf1, wt3, buf0, N);
  k_agg<<<ablocks, 256, 0, stream>>>(buf0, deg, row_ptr, csr_src, csr_norm, b3, buf1, N);

  int pblocks = (N + 127) / 128;  // 4 waves/block, 32 nodes/wave
  k_pool<<<pblocks, 256, 0, stream>>>(buf1, bv, pooled, N);
  k_final<<<B, 64, 0, stream>>>(pooled, lw, lb, out);
}

// Round 4
// 504.281 us; speedup vs baseline: 2.2208x; 1.1879x over previous
//
#include <hip/hip_runtime.h>

typedef __attribute__((ext_vector_type(8))) short bf16x8;
typedef __attribute__((ext_vector_type(4))) float f32x4;

__device__ __forceinline__ ushort f2bf(float f) {
  union { float f; uint u; } v; v.f = f;
  uint r = (v.u + 0x7fffu + ((v.u >> 16) & 1u)) >> 16;
  return (ushort)r;
}
__device__ __forceinline__ float2 bfp2f(uint p) {  // packed 2x bf16 -> 2x f32
  union { uint u; float f; } lo, hi;
  lo.u = p << 16; hi.u = p & 0xffff0000u;
  float2 r; r.x = lo.f; r.y = hi.f; return r;
}

// ---------------- CSR build ----------------
// dc[i]: bits[43:0] = degree in 32.12-ish fixed point (w * 2^32), bits[63:44] = edge count.
// Self-loop weight 1.0 pre-seeded as 1<<32. One u64 atomic per edge replaces
// the previous {float deg, int cnt} atomic pair (atomic-throughput-bound).

__global__ void k_init(unsigned long long* dc, int* cursor, int* row_ptr,
                       float* pooled, int N, int pooledN) {
  int i = blockIdx.x * blockDim.x + threadIdx.x;
  if (i < N) { dc[i] = 1ull << 32; cursor[i] = 0; }
  if (i < pooledN) pooled[i] = 0.0f;
  if (i == 0) row_ptr[0] = 0;
}

__global__ void k_edge1(const int* __restrict__ ei, const float* __restrict__ ew,
                        unsigned long long* dc, int E) {
  int stride = gridDim.x * blockDim.x;
  for (int e = blockIdx.x * blockDim.x + threadIdx.x; e < E; e += stride) {
    int dst = ei[E + e];
    unsigned long long fixed = (unsigned long long)(ew[e] * 4294967296.0f);
    atomicAdd(&dc[dst], (1ull << 44) + fixed);
  }
}

__global__ void k_dinv(const unsigned long long* __restrict__ dc,
                       float* dinv, int* cnt, int N) {
  int i = blockIdx.x * blockDim.x + threadIdx.x;
  if (i < N) {
    unsigned long long v = dc[i];
    cnt[i] = (int)(v >> 44);
    float deg = (float)(v & 0xFFFFFFFFFFFull) * 0x1p-32f;  // >= 1.0 always
    dinv[i] = rsqrtf(deg);
  }
}

__global__ void k_scan1(const int* __restrict__ cnt, int* row_ptr, int* bsum, int N) {
  __shared__ int s[1024];
  int t = threadIdx.x;
  int i = blockIdx.x * 1024 + t;
  s[t] = (i < N) ? cnt[i] : 0;
  __syncthreads();
  for (int d = 1; d < 1024; d <<= 1) {
    int add = (t >= d) ? s[t - d] : 0;
    __syncthreads();
    s[t] += add;
    __syncthreads();
  }
  if (i < N) row_ptr[i + 1] = s[t];
  if (t == 1023) bsum[blockIdx.x] = s[1023];
}

__global__ void k_scan2(int* bsum, int nb) {
  if (threadIdx.x == 0 && blockIdx.x == 0) {
    int off = 0;
    for (int j = 0; j < nb; ++j) { int t = bsum[j]; bsum[j] = off; off += t; }
  }
}

__global__ void k_scan3(int* row_ptr, const int* __restrict__ bsum, int N) {
  int i = blockIdx.x * blockDim.x + threadIdx.x;
  if (i < N) {
    int b = i >> 10;
    if (b > 0) row_ptr[i + 1] += bsum[b];
  }
}

__global__ void k_edge2(const int* __restrict__ ei, const float* __restrict__ ew,
                        const float* __restrict__ dinv, const int* __restrict__ row_ptr,
                        int* cursor, int* csr_src, float* csr_norm, int E) {
  int stride = gridDim.x * blockDim.x;
  for (int e = blockIdx.x * blockDim.x + threadIdx.x; e < E; e += stride) {
    int src = ei[e];
    int dst = ei[E + e];
    int pos = row_ptr[dst] + atomicAdd(&cursor[dst], 1);
    csr_src[pos] = src;
    csr_norm[pos] = dinv[src] * ew[e] * dinv[dst];
  }
}

// ---------------- weight transpose + cast: Wt[c][k] = bf16(W[k][c]) ----------------

__global__ void k_wt3(const float* __restrict__ W1, const float* __restrict__ W2,
                      const float* __restrict__ W3, ushort* T1, ushort* T2, ushort* T3) {
  int which = blockIdx.x >> 6;
  const float* W = which == 0 ? W1 : (which == 1 ? W2 : W3);
  ushort* T = which == 0 ? T1 : (which == 1 ? T2 : T3);
  int idx = (blockIdx.x & 63) * 256 + threadIdx.x;  // 64 blocks * 256 = 16384
  int k = idx >> 7, c = idx & 127;
  T[c * 128 + k] = f2bf(W[idx]);
}

// ---------------- MFMA GEMM: C[N,128](bf16) = A[N,128] @ W[128,128] ----------------

template<int AF32>
__global__ __launch_bounds__(256) void k_gemm(const void* __restrict__ Ap,
                                              const ushort* __restrict__ Wt,
                                              ushort* __restrict__ C, int N) {
  int wid = threadIdx.x >> 6, lane = threadIdx.x & 63;
  int row0 = blockIdx.x * 64 + wid * 16;
  int r = lane & 15, kh = lane >> 4;  // A/B frag: row/col = r, k = kh*8 + j
  int arow = row0 + r;
  bool inb = arow < N;
  bf16x8 afrag[4];
#pragma unroll
  for (int kc = 0; kc < 4; ++kc) {
    if (inb) {
      if constexpr (AF32) {
        const float* A = (const float*)Ap;
        const float* p = &A[(size_t)arow * 128 + kc * 32 + kh * 8];
        float4 x0 = *(const float4*)p;
        float4 x1 = *(const float4*)(p + 4);
        bf16x8 t;
        t[0] = (short)f2bf(x0.x); t[1] = (short)f2bf(x0.y);
        t[2] = (short)f2bf(x0.z); t[3] = (short)f2bf(x0.w);
        t[4] = (short)f2bf(x1.x); t[5] = (short)f2bf(x1.y);
        t[6] = (short)f2bf(x1.z); t[7] = (short)f2bf(x1.w);
        afrag[kc] = t;
      } else {
        const ushort* A = (const ushort*)Ap;
        afrag[kc] = *(const bf16x8*)&A[(size_t)arow * 128 + kc * 32 + kh * 8];
      }
    } else {
      bf16x8 z = {0, 0, 0, 0, 0, 0, 0, 0};
      afrag[kc] = z;
    }
  }
  f32x4 acc[8];
#pragma unroll
  for (int ct = 0; ct < 8; ++ct) { f32x4 z = {0.f, 0.f, 0.f, 0.f}; acc[ct] = z; }
#pragma unroll
  for (int ct = 0; ct < 8; ++ct) {
#pragma unroll
    for (int kc = 0; kc < 4; ++kc) {
      bf16x8 b = *(const bf16x8*)&Wt[(size_t)(ct * 16 + r) * 128 + kc * 32 + kh * 8];
      acc[ct] = __builtin_amdgcn_mfma_f32_16x16x32_bf16(afrag[kc], b, acc[ct], 0, 0, 0);
    }
  }
  // C/D layout: col = lane&15 (=r), row-in-tile = kh*4 + rr
#pragma unroll
  for (int ct = 0; ct < 8; ++ct) {
#pragma unroll
    for (int rr = 0; rr < 4; ++rr) {
      int row = row0 + kh * 4 + rr;
      if (row < N) C[(size_t)row * 128 + ct * 16 + r] = f2bf(acc[ct][rr]);
    }
  }
}

// ---------------- Aggregation: out = relu(Ahat @ xw + b), bf16 in/out ----------------
// one wave per node; lane l owns features 2l, 2l+1. 8 gathers in flight.

__global__ __launch_bounds__(256) void k_agg(const ushort* __restrict__ xw,
                                             const float* __restrict__ dinv,
                                             const int* __restrict__ row_ptr,
                                             const int* __restrict__ csr_src,
                                             const float* __restrict__ csr_norm,
                                             const float* __restrict__ bias,
                                             ushort* __restrict__ out, int N) {
  int wid = threadIdx.x >> 6, lane = threadIdx.x & 63;
  int node = blockIdx.x * 4 + wid;
  if (node >= N) return;
  float di = dinv[node];
  uint selfp = *(const uint*)&xw[(size_t)node * 128 + lane * 2];
  float2 sv = bfp2f(selfp);
  float w0 = di * di;
  float2 a0 = {sv.x * w0, sv.y * w0};
  float2 a1 = {0.f, 0.f}, a2 = {0.f, 0.f}, a3 = {0.f, 0.f};
  int s = row_ptr[node], e = row_ptr[node + 1];
  int i = s;
  for (; i + 8 <= e; i += 8) {
    int s0 = csr_src[i],     s1 = csr_src[i + 1], s2 = csr_src[i + 2], s3 = csr_src[i + 3];
    int s4 = csr_src[i + 4], s5 = csr_src[i + 5], s6 = csr_src[i + 6], s7 = csr_src[i + 7];
    float n0 = csr_norm[i],     n1 = csr_norm[i + 1], n2 = csr_norm[i + 2], n3 = csr_norm[i + 3];
    float n4 = csr_norm[i + 4], n5 = csr_norm[i + 5], n6 = csr_norm[i + 6], n7 = csr_norm[i + 7];
    uint g0 = *(const uint*)&xw[(size_t)s0 * 128 + lane * 2];
    uint g1 = *(const uint*)&xw[(size_t)s1 * 128 + lane * 2];
    uint g2 = *(const uint*)&xw[(size_t)s2 * 128 + lane * 2];
    uint g3 = *(const uint*)&xw[(size_t)s3 * 128 + lane * 2];
    uint g4 = *(const uint*)&xw[(size_t)s4 * 128 + lane * 2];
    uint g5 = *(const uint*)&xw[(size_t)s5 * 128 + lane * 2];
    uint g6 = *(const uint*)&xw[(size_t)s6 * 128 + lane * 2];
    uint g7 = *(const uint*)&xw[(size_t)s7 * 128 + lane * 2];
    float2 f0 = bfp2f(g0), f1 = bfp2f(g1), f2 = bfp2f(g2), f3 = bfp2f(g3);
    float2 f4 = bfp2f(g4), f5 = bfp2f(g5), f6 = bfp2f(g6), f7 = bfp2f(g7);
    a0.x = fmaf(n0, f0.x, a0.x); a0.y = fmaf(n0, f0.y, a0.y);
    a1.x = fmaf(n1, f1.x, a1.x); a1.y = fmaf(n1, f1.y, a1.y);
    a2.x = fmaf(n2, f2.x, a2.x); a2.y = fmaf(n2, f2.y, a2.y);
    a3.x = fmaf(n3, f3.x, a3.x); a3.y = fmaf(n3, f3.y, a3.y);
    a0.x = fmaf(n4, f4.x, a0.x); a0.y = fmaf(n4, f4.y, a0.y);
    a1.x = fmaf(n5, f5.x, a1.x); a1.y = fmaf(n5, f5.y, a1.y);
    a2.x = fmaf(n6, f6.x, a2.x); a2.y = fmaf(n6, f6.y, a2.y);
    a3.x = fmaf(n7, f7.x, a3.x); a3.y = fmaf(n7, f7.y, a3.y);
  }
  for (; i + 4 <= e; i += 4) {
    int s0 = csr_src[i], s1 = csr_src[i + 1], s2 = csr_src[i + 2], s3 = csr_src[i + 3];
    float n0 = csr_norm[i], n1 = csr_norm[i + 1], n2 = csr_norm[i + 2], n3 = csr_norm[i + 3];
    uint g0 = *(const uint*)&xw[(size_t)s0 * 128 + lane * 2];
    uint g1 = *(const uint*)&xw[(size_t)s1 * 128 + lane * 2];
    uint g2 = *(const uint*)&xw[(size_t)s2 * 128 + lane * 2];
    uint g3 = *(const uint*)&xw[(size_t)s3 * 128 + lane * 2];
    float2 f0 = bfp2f(g0), f1 = bfp2f(g1), f2 = bfp2f(g2), f3 = bfp2f(g3);
    a0.x = fmaf(n0, f0.x, a0.x); a0.y = fmaf(n0, f0.y, a0.y);
    a1.x = fmaf(n1, f1.x, a1.x); a1.y = fmaf(n1, f1.y, a1.y);
    a2.x = fmaf(n2, f2.x, a2.x); a2.y = fmaf(n2, f2.y, a2.y);
    a3.x = fmaf(n3, f3.x, a3.x); a3.y = fmaf(n3, f3.y, a3.y);
  }
  for (; i < e; ++i) {
    int s0 = csr_src[i]; float n0 = csr_norm[i];
    uint g0 = *(const uint*)&xw[(size_t)s0 * 128 + lane * 2];
    float2 f0 = bfp2f(g0);
    a0.x = fmaf(n0, f0.x, a0.x); a0.y = fmaf(n0, f0.y, a0.y);
  }
  float bx = bias[lane * 2], by = bias[lane * 2 + 1];
  float rx = fmaxf(a0.x + a1.x + a2.x + a3.x + bx, 0.f);
  float ry = fmaxf(a0.y + a1.y + a2.y + a3.y + by, 0.f);
  ushort2 o = {f2bf(rx), f2bf(ry)};
  *(ushort2*)&out[(size_t)node * 128 + lane * 2] = o;
}

// ---------------- Pooling: one wave per 32-node chunk, lane owns 2 features ----------------

__global__ __launch_bounds__(256) void k_pool(const ushort* __restrict__ x,
                                              const int* __restrict__ batch,
                                              float* pooled, int N) {
  int wid = threadIdx.x >> 6, lane = threadIdx.x & 63;
  int n0 = (blockIdx.x * 4 + wid) * 32;
  if (n0 >= N) return;
  int n1 = min(n0 + 32, N);
  int cur = batch[n0];
  float ax = 0.f, ay = 0.f;
  for (int n = n0; n < n1; ++n) {
    int b = batch[n];
    if (b != cur) {
      atomicAdd(&pooled[cur * 128 + lane * 2], ax);
      atomicAdd(&pooled[cur * 128 + lane * 2 + 1], ay);
      ax = 0.f; ay = 0.f;
      cur = b;
    }
    uint p = *(const uint*)&x[(size_t)n * 128 + lane * 2];
    float2 f = bfp2f(p);
    ax += f.x; ay += f.y;
  }
  atomicAdd(&pooled[cur * 128 + lane * 2], ax);
  atomicAdd(&pooled[cur * 128 + lane * 2 + 1], ay);
}

__global__ void k_final(const float* __restrict__ pooled, const float* __restrict__ lw,
                        const float* __restrict__ lb, float* __restrict__ out) {
  int b = blockIdx.x;
  int l = threadIdx.x;  // 64
  float s = pooled[b * 128 + l] * lw[l] + pooled[b * 128 + 64 + l] * lw[64 + l];
#pragma unroll
  for (int o = 32; o > 0; o >>= 1) s += __shfl_down(s, o, 64);
  if (l == 0) out[b] = s + lb[0];
}

// ---------------- host ----------------

extern "C" void kernel_launch(void* const* d_in, const int* in_sizes, int n_in,
                              void* d_out, int out_size, void* d_ws, size_t ws_size,
                              hipStream_t stream) {
  const float* X  = (const float*)d_in[0];
  const int*   ei = (const int*)d_in[1];
  const float* ew = (const float*)d_in[2];
  const int*   bv = (const int*)d_in[3];
  const float* W1 = (const float*)d_in[4];
  const float* b1 = (const float*)d_in[5];
  const float* W2 = (const float*)d_in[6];
  const float* b2 = (const float*)d_in[7];
  const float* W3 = (const float*)d_in[8];
  const float* b3 = (const float*)d_in[9];
  const float* lw = (const float*)d_in[10];
  const float* lb = (const float*)d_in[11];
  float* out = (float*)d_out;

  int N = in_sizes[0] / 128;
  int E = in_sizes[2];
  int B = out_size;

  char* wsp = (char*)d_ws;
  size_t off = 0;
  auto alloc = [&](size_t bytes) -> void* {
    void* p = wsp + off;
    off += (bytes + 255) & ~(size_t)255;
    return p;
  };
  unsigned long long* dc = (unsigned long long*)alloc((size_t)N * 8);
  float*  dinv     = (float*)alloc((size_t)N * 4);
  int*    cnt      = (int*)alloc((size_t)N * 4);
  int*    cursor   = (int*)alloc((size_t)N * 4);
  int*    row_ptr  = (int*)alloc((size_t)(N + 1) * 4);
  int*    bsum     = (int*)alloc(256 * 4);
  int*    csr_src  = (int*)alloc((size_t)E * 4);
  float*  csr_norm = (float*)alloc((size_t)E * 4);
  ushort* wt1      = (ushort*)alloc(128 * 128 * 2);
  ushort* wt2      = (ushort*)alloc(128 * 128 * 2);
  ushort* wt3      = (ushort*)alloc(128 * 128 * 2);
  ushort* buf0     = (ushort*)alloc((size_t)N * 128 * 2);  // xw scratch (bf16)
  ushort* buf1     = (ushort*)alloc((size_t)N * 128 * 2);  // h scratch (bf16)
  float*  pooled   = (float*)alloc((size_t)B * 128 * 4);
  (void)ws_size; (void)n_in;

  int nthr = 256;
  int nb_n = (N + nthr - 1) / nthr;
  int nb1 = (N + 1023) / 1024;

  k_init<<<nb_n, nthr, 0, stream>>>(dc, cursor, row_ptr, pooled, N, B * 128);
  k_edge1<<<2048, 256, 0, stream>>>(ei, ew, dc, E);
  k_dinv<<<nb_n, nthr, 0, stream>>>(dc, dinv, cnt, N);
  k_scan1<<<nb1, 1024, 0, stream>>>(cnt, row_ptr, bsum, N);
  k_scan2<<<1, 64, 0, stream>>>(bsum, nb1);
  k_scan3<<<nb_n, nthr, 0, stream>>>(row_ptr, bsum, N);
  k_edge2<<<2048, 256, 0, stream>>>(ei, ew, dinv, row_ptr, cursor, csr_src, csr_norm, E);
  k_wt3<<<192, 256, 0, stream>>>(W1, W2, W3, wt1, wt2, wt3);

  int gblocks = (N + 63) / 64;
  int ablocks = (N + 3) / 4;
  // layer 1 (A = X fp32)
  k_gemm<1><<<gblocks, 256, 0, stream>>>(X, wt1, buf0, N);
  k_agg<<<ablocks, 256, 0, stream>>>(buf0, dinv, row_ptr, csr_src, csr_norm, b1, buf1, N);
  // layer 2
  k_gemm<0><<<gblocks, 256, 0, stream>>>(buf1, wt2, buf0, N);
  k_agg<<<ablocks, 256, 0, stream>>>(buf0, dinv, row_ptr, csr_src, csr_norm, b2, buf1, N);
  // layer 3
  k_gemm<0><<<gblocks, 256, 0, stream>>>(buf1, wt3, buf0, N);
  k_agg<<<ablocks, 256, 0, stream>>>(buf0, dinv, row_ptr, csr_src, csr_norm, b3, buf1, N);

  int pblocks = (N + 127) / 128;  // 4 waves/block, 32 nodes/wave
  k_pool<<<pblocks, 256, 0, stream>>>(buf1, bv, pooled, N);
  k_final<<<B, 64, 0, stream>>>(pooled, lw, lb, out);
}

// Round 5
// 498.479 us; speedup vs baseline: 2.2466x; 1.0116x over previous
//
#include <hip/hip_runtime.h>

typedef __attribute__((ext_vector_type(8))) short bf16x8;
typedef __attribute__((ext_vector_type(4))) float f32x4;

__device__ __forceinline__ ushort f2bf(float f) {
  union { float f; uint u; } v; v.f = f;
  uint r = (v.u + 0x7fffu + ((v.u >> 16) & 1u)) >> 16;
  return (ushort)r;
}
__device__ __forceinline__ float2 bfp2f(uint p) {  // packed 2x bf16 -> 2x f32
  union { uint u; float f; } lo, hi;
  lo.u = p << 16; hi.u = p & 0xffff0000u;
  float2 r; r.x = lo.f; r.y = hi.f; return r;
}
__device__ __forceinline__ float u2f(uint u) {
  union { uint u; float f; } v; v.u = u; return v.f;
}
__device__ __forceinline__ uint f2u(float f) {
  union { float f; uint u; } v; v.f = f; return v.u;
}

// ---------------- CSR build ----------------
// dc[i]: bits[43:0] = degree in fixed point (w * 2^32), bits[63:44] = edge count.
// csr[pos]: bits[31:0] = src node, bits[63:32] = norm (fp32 bits) -- single
// 8B scattered store per edge instead of two 4B stores to separate arrays.

__global__ void k_init(unsigned long long* dc, int* cursor, int* row_ptr,
                       float* pooled, int N, int pooledN) {
  int i = blockIdx.x * blockDim.x + threadIdx.x;
  if (i < N) { dc[i] = 1ull << 32; cursor[i] = 0; }
  if (i < pooledN) pooled[i] = 0.0f;
  if (i == 0) row_ptr[0] = 0;
}

__global__ void k_edge1(const int* __restrict__ ei, const float* __restrict__ ew,
                        unsigned long long* dc, int E) {
  int stride = gridDim.x * blockDim.x;
  for (int e = blockIdx.x * blockDim.x + threadIdx.x; e < E; e += stride) {
    int dst = ei[E + e];
    unsigned long long fixed = (unsigned long long)(ew[e] * 4294967296.0f);
    atomicAdd(&dc[dst], (1ull << 44) + fixed);
  }
}

__global__ void k_dinv(const unsigned long long* __restrict__ dc,
                       float* dinv, int* cnt, int N) {
  int i = blockIdx.x * blockDim.x + threadIdx.x;
  if (i < N) {
    unsigned long long v = dc[i];
    cnt[i] = (int)(v >> 44);
    float deg = (float)(v & 0xFFFFFFFFFFFull) * 0x1p-32f;  // >= 1.0 always
    dinv[i] = rsqrtf(deg);
  }
}

__global__ void k_scan1(const int* __restrict__ cnt, int* row_ptr, int* bsum, int N) {
  __shared__ int s[1024];
  int t = threadIdx.x;
  int i = blockIdx.x * 1024 + t;
  s[t] = (i < N) ? cnt[i] : 0;
  __syncthreads();
  for (int d = 1; d < 1024; d <<= 1) {
    int add = (t >= d) ? s[t - d] : 0;
    __syncthreads();
    s[t] += add;
    __syncthreads();
  }
  if (i < N) row_ptr[i + 1] = s[t];
  if (t == 1023) bsum[blockIdx.x] = s[1023];
}

__global__ void k_scan2(int* bsum, int nb) {
  if (threadIdx.x == 0 && blockIdx.x == 0) {
    int off = 0;
    for (int j = 0; j < nb; ++j) { int t = bsum[j]; bsum[j] = off; off += t; }
  }
}

__global__ void k_scan3(int* row_ptr, const int* __restrict__ bsum, int N) {
  int i = blockIdx.x * blockDim.x + threadIdx.x;
  if (i < N) {
    int b = i >> 10;
    if (b > 0) row_ptr[i + 1] += bsum[b];
  }
}

__global__ void k_edge2(const int* __restrict__ ei, const float* __restrict__ ew,
                        const float* __restrict__ dinv, const int* __restrict__ row_ptr,
                        int* cursor, unsigned long long* csr, int E) {
  int stride = gridDim.x * blockDim.x;
  for (int e = blockIdx.x * blockDim.x + threadIdx.x; e < E; e += stride) {
    int src = ei[e];
    int dst = ei[E + e];
    int pos = row_ptr[dst] + atomicAdd(&cursor[dst], 1);
    float norm = dinv[src] * ew[e] * dinv[dst];
    csr[pos] = (unsigned long long)(uint)src |
               ((unsigned long long)f2u(norm) << 32);
  }
}

// ---------------- weight transpose + cast: Wt[c][k] = bf16(W[k][c]) ----------------

__global__ void k_wt3(const float* __restrict__ W1, const float* __restrict__ W2,
                      const float* __restrict__ W3, ushort* T1, ushort* T2, ushort* T3) {
  int which = blockIdx.x >> 6;
  const float* W = which == 0 ? W1 : (which == 1 ? W2 : W3);
  ushort* T = which == 0 ? T1 : (which == 1 ? T2 : T3);
  int idx = (blockIdx.x & 63) * 256 + threadIdx.x;  // 64 blocks * 256 = 16384
  int k = idx >> 7, c = idx & 127;
  T[c * 128 + k] = f2bf(W[idx]);
}

// ---------------- MFMA GEMM: C[N,128](bf16) = A[N,128] @ W[128,128] ----------------

template<int AF32>
__global__ __launch_bounds__(256) void k_gemm(const void* __restrict__ Ap,
                                              const ushort* __restrict__ Wt,
                                              ushort* __restrict__ C, int N) {
  int wid = threadIdx.x >> 6, lane = threadIdx.x & 63;
  int row0 = blockIdx.x * 64 + wid * 16;
  int r = lane & 15, kh = lane >> 4;  // A/B frag: row/col = r, k = kh*8 + j
  int arow = row0 + r;
  bool inb = arow < N;
  bf16x8 afrag[4];
#pragma unroll
  for (int kc = 0; kc < 4; ++kc) {
    if (inb) {
      if constexpr (AF32) {
        const float* A = (const float*)Ap;
        const float* p = &A[(size_t)arow * 128 + kc * 32 + kh * 8];
        float4 x0 = *(const float4*)p;
        float4 x1 = *(const float4*)(p + 4);
        bf16x8 t;
        t[0] = (short)f2bf(x0.x); t[1] = (short)f2bf(x0.y);
        t[2] = (short)f2bf(x0.z); t[3] = (short)f2bf(x0.w);
        t[4] = (short)f2bf(x1.x); t[5] = (short)f2bf(x1.y);
        t[6] = (short)f2bf(x1.z); t[7] = (short)f2bf(x1.w);
        afrag[kc] = t;
      } else {
        const ushort* A = (const ushort*)Ap;
        afrag[kc] = *(const bf16x8*)&A[(size_t)arow * 128 + kc * 32 + kh * 8];
      }
    } else {
      bf16x8 z = {0, 0, 0, 0, 0, 0, 0, 0};
      afrag[kc] = z;
    }
  }
  f32x4 acc[8];
#pragma unroll
  for (int ct = 0; ct < 8; ++ct) { f32x4 z = {0.f, 0.f, 0.f, 0.f}; acc[ct] = z; }
#pragma unroll
  for (int ct = 0; ct < 8; ++ct) {
#pragma unroll
    for (int kc = 0; kc < 4; ++kc) {
      bf16x8 b = *(const bf16x8*)&Wt[(size_t)(ct * 16 + r) * 128 + kc * 32 + kh * 8];
      acc[ct] = __builtin_amdgcn_mfma_f32_16x16x32_bf16(afrag[kc], b, acc[ct], 0, 0, 0);
    }
  }
  // C/D layout: col = lane&15 (=r), row-in-tile = kh*4 + rr
#pragma unroll
  for (int ct = 0; ct < 8; ++ct) {
#pragma unroll
    for (int rr = 0; rr < 4; ++rr) {
      int row = row0 + kh * 4 + rr;
      if (row < N) C[(size_t)row * 128 + ct * 16 + r] = f2bf(acc[ct][rr]);
    }
  }
}

// ---------------- Aggregation: out = relu(Ahat @ xw + b), bf16 in/out ----------------
// one wave per node; lane l owns features 2l, 2l+1. 8 gathers in flight.
// csr entry: low 32 = src, high 32 = norm bits.

__global__ __launch_bounds__(256) void k_agg(const ushort* __restrict__ xw,
                                             const float* __restrict__ dinv,
                                             const int* __restrict__ row_ptr,
                                             const unsigned long long* __restrict__ csr,
                                             const float* __restrict__ bias,
                                             ushort* __restrict__ out, int N) {
  int wid = threadIdx.x >> 6, lane = threadIdx.x & 63;
  int node = blockIdx.x * 4 + wid;
  if (node >= N) return;
  float di = dinv[node];
  uint selfp = *(const uint*)&xw[(size_t)node * 128 + lane * 2];
  float2 sv = bfp2f(selfp);
  float w0 = di * di;
  float2 a0 = {sv.x * w0, sv.y * w0};
  float2 a1 = {0.f, 0.f}, a2 = {0.f, 0.f}, a3 = {0.f, 0.f};
  int s = row_ptr[node], e = row_ptr[node + 1];
  int i = s;
  for (; i + 8 <= e; i += 8) {
    unsigned long long c0 = csr[i],     c1 = csr[i + 1], c2 = csr[i + 2], c3 = csr[i + 3];
    unsigned long long c4 = csr[i + 4], c5 = csr[i + 5], c6 = csr[i + 6], c7 = csr[i + 7];
    uint g0 = *(const uint*)&xw[(size_t)(uint)c0 * 128 + lane * 2];
    uint g1 = *(const uint*)&xw[(size_t)(uint)c1 * 128 + lane * 2];
    uint g2 = *(const uint*)&xw[(size_t)(uint)c2 * 128 + lane * 2];
    uint g3 = *(const uint*)&xw[(size_t)(uint)c3 * 128 + lane * 2];
    uint g4 = *(const uint*)&xw[(size_t)(uint)c4 * 128 + lane * 2];
    uint g5 = *(const uint*)&xw[(size_t)(uint)c5 * 128 + lane * 2];
    uint g6 = *(const uint*)&xw[(size_t)(uint)c6 * 128 + lane * 2];
    uint g7 = *(const uint*)&xw[(size_t)(uint)c7 * 128 + lane * 2];
    float n0 = u2f((uint)(c0 >> 32)), n1 = u2f((uint)(c1 >> 32));
    float n2 = u2f((uint)(c2 >> 32)), n3 = u2f((uint)(c3 >> 32));
    float n4 = u2f((uint)(c4 >> 32)), n5 = u2f((uint)(c5 >> 32));
    float n6 = u2f((uint)(c6 >> 32)), n7 = u2f((uint)(c7 >> 32));
    float2 f0 = bfp2f(g0), f1 = bfp2f(g1), f2 = bfp2f(g2), f3 = bfp2f(g3);
    float2 f4 = bfp2f(g4), f5 = bfp2f(g5), f6 = bfp2f(g6), f7 = bfp2f(g7);
    a0.x = fmaf(n0, f0.x, a0.x); a0.y = fmaf(n0, f0.y, a0.y);
    a1.x = fmaf(n1, f1.x, a1.x); a1.y = fmaf(n1, f1.y, a1.y);
    a2.x = fmaf(n2, f2.x, a2.x); a2.y = fmaf(n2, f2.y, a2.y);
    a3.x = fmaf(n3, f3.x, a3.x); a3.y = fmaf(n3, f3.y, a3.y);
    a0.x = fmaf(n4, f4.x, a0.x); a0.y = fmaf(n4, f4.y, a0.y);
    a1.x = fmaf(n5, f5.x, a1.x); a1.y = fmaf(n5, f5.y, a1.y);
    a2.x = fmaf(n6, f6.x, a2.x); a2.y = fmaf(n6, f6.y, a2.y);
    a3.x = fmaf(n7, f7.x, a3.x); a3.y = fmaf(n7, f7.y, a3.y);
  }
  for (; i + 4 <= e; i += 4) {
    unsigned long long c0 = csr[i], c1 = csr[i + 1], c2 = csr[i + 2], c3 = csr[i + 3];
    uint g0 = *(const uint*)&xw[(size_t)(uint)c0 * 128 + lane * 2];
    uint g1 = *(const uint*)&xw[(size_t)(uint)c1 * 128 + lane * 2];
    uint g2 = *(const uint*)&xw[(size_t)(uint)c2 * 128 + lane * 2];
    uint g3 = *(const uint*)&xw[(size_t)(uint)c3 * 128 + lane * 2];
    float n0 = u2f((uint)(c0 >> 32)), n1 = u2f((uint)(c1 >> 32));
    float n2 = u2f((uint)(c2 >> 32)), n3 = u2f((uint)(c3 >> 32));
    float2 f0 = bfp2f(g0), f1 = bfp2f(g1), f2 = bfp2f(g2), f3 = bfp2f(g3);
    a0.x = fmaf(n0, f0.x, a0.x); a0.y = fmaf(n0, f0.y, a0.y);
    a1.x = fmaf(n1, f1.x, a1.x); a1.y = fmaf(n1, f1.y, a1.y);
    a2.x = fmaf(n2, f2.x, a2.x); a2.y = fmaf(n2, f2.y, a2.y);
    a3.x = fmaf(n3, f3.x, a3.x); a3.y = fmaf(n3, f3.y, a3.y);
  }
  for (; i < e; ++i) {
    unsigned long long c0 = csr[i];
    uint g0 = *(const uint*)&xw[(size_t)(uint)c0 * 128 + lane * 2];
    float n0 = u2f((uint)(c0 >> 32));
    float2 f0 = bfp2f(g0);
    a0.x = fmaf(n0, f0.x, a0.x); a0.y = fmaf(n0, f0.y, a0.y);
  }
  float bx = bias[lane * 2], by = bias[lane * 2 + 1];
  float rx = fmaxf(a0.x + a1.x + a2.x + a3.x + bx, 0.f);
  float ry = fmaxf(a0.y + a1.y + a2.y + a3.y + by, 0.f);
  ushort2 o = {f2bf(rx), f2bf(ry)};
  *(ushort2*)&out[(size_t)node * 128 + lane * 2] = o;
}

// ---------------- Pooling: one wave per 32-node chunk, lane owns 2 features ----------------

__global__ __launch_bounds__(256) void k_pool(const ushort* __restrict__ x,
                                              const int* __restrict__ batch,
                                              float* pooled, int N) {
  int wid = threadIdx.x >> 6, lane = threadIdx.x & 63;
  int n0 = (blockIdx.x * 4 + wid) * 32;
  if (n0 >= N) return;
  int n1 = min(n0 + 32, N);
  int cur = batch[n0];
  float ax = 0.f, ay = 0.f;
  for (int n = n0; n < n1; ++n) {
    int b = batch[n];
    if (b != cur) {
      atomicAdd(&pooled[cur * 128 + lane * 2], ax);
      atomicAdd(&pooled[cur * 128 + lane * 2 + 1], ay);
      ax = 0.f; ay = 0.f;
      cur = b;
    }
    uint p = *(const uint*)&x[(size_t)n * 128 + lane * 2];
    float2 f = bfp2f(p);
    ax += f.x; ay += f.y;
  }
  atomicAdd(&pooled[cur * 128 + lane * 2], ax);
  atomicAdd(&pooled[cur * 128 + lane * 2 + 1], ay);
}

__global__ void k_final(const float* __restrict__ pooled, const float* __restrict__ lw,
                        const float* __restrict__ lb, float* __restrict__ out) {
  int b = blockIdx.x;
  int l = threadIdx.x;  // 64
  float s = pooled[b * 128 + l] * lw[l] + pooled[b * 128 + 64 + l] * lw[64 + l];
#pragma unroll
  for (int o = 32; o > 0; o >>= 1) s += __shfl_down(s, o, 64);
  if (l == 0) out[b] = s + lb[0];
}

// ---------------- host ----------------

extern "C" void kernel_launch(void* const* d_in, const int* in_sizes, int n_in,
                              void* d_out, int out_size, void* d_ws, size_t ws_size,
                              hipStream_t stream) {
  const float* X  = (const float*)d_in[0];
  const int*   ei = (const int*)d_in[1];
  const float* ew = (const float*)d_in[2];
  const int*   bv = (const int*)d_in[3];
  const float* W1 = (const float*)d_in[4];
  const float* b1 = (const float*)d_in[5];
  const float* W2 = (const float*)d_in[6];
  const float* b2 = (const float*)d_in[7];
  const float* W3 = (const float*)d_in[8];
  const float* b3 = (const float*)d_in[9];
  const float* lw = (const float*)d_in[10];
  const float* lb = (const float*)d_in[11];
  float* out = (float*)d_out;

  int N = in_sizes[0] / 128;
  int E = in_sizes[2];
  int B = out_size;

  char* wsp = (char*)d_ws;
  size_t off = 0;
  auto alloc = [&](size_t bytes) -> void* {
    void* p = wsp + off;
    off += (bytes + 255) & ~(size_t)255;
    return p;
  };
  unsigned long long* dc = (unsigned long long*)alloc((size_t)N * 8);
  float*  dinv     = (float*)alloc((size_t)N * 4);
  int*    cnt      = (int*)alloc((size_t)N * 4);
  int*    cursor   = (int*)alloc((size_t)N * 4);
  int*    row_ptr  = (int*)alloc((size_t)(N + 1) * 4);
  int*    bsum     = (int*)alloc(256 * 4);
  unsigned long long* csr = (unsigned long long*)alloc((size_t)E * 8);
  ushort* wt1      = (ushort*)alloc(128 * 128 * 2);
  ushort* wt2      = (ushort*)alloc(128 * 128 * 2);
  ushort* wt3      = (ushort*)alloc(128 * 128 * 2);
  ushort* buf0     = (ushort*)alloc((size_t)N * 128 * 2);  // xw scratch (bf16)
  ushort* buf1     = (ushort*)alloc((size_t)N * 128 * 2);  // h scratch (bf16)
  float*  pooled   = (float*)alloc((size_t)B * 128 * 4);
  (void)ws_size; (void)n_in;

  int nthr = 256;
  int nb_n = (N + nthr - 1) / nthr;
  int nb1 = (N + 1023) / 1024;

  k_init<<<nb_n, nthr, 0, stream>>>(dc, cursor, row_ptr, pooled, N, B * 128);
  k_edge1<<<2048, 256, 0, stream>>>(ei, ew, dc, E);
  k_dinv<<<nb_n, nthr, 0, stream>>>(dc, dinv, cnt, N);
  k_scan1<<<nb1, 1024, 0, stream>>>(cnt, row_ptr, bsum, N);
  k_scan2<<<1, 64, 0, stream>>>(bsum, nb1);
  k_scan3<<<nb_n, nthr, 0, stream>>>(row_ptr, bsum, N);
  k_edge2<<<2048, 256, 0, stream>>>(ei, ew, dinv, row_ptr, cursor, csr, E);
  k_wt3<<<192, 256, 0, stream>>>(W1, W2, W3, wt1, wt2, wt3);

  int gblocks = (N + 63) / 64;
  int ablocks = (N + 3) / 4;
  // layer 1 (A = X fp32)
  k_gemm<1><<<gblocks, 256, 0, stream>>>(X, wt1, buf0, N);
  k_agg<<<ablocks, 256, 0, stream>>>(buf0, dinv, row_ptr, csr, b1, buf1, N);
  // layer 2
  k_gemm<0><<<gblocks, 256, 0, stream>>>(buf1, wt2, buf0, N);
  k_agg<<<ablocks, 256, 0, stream>>>(buf0, dinv, row_ptr, csr, b2, buf1, N);
  // layer 3
  k_gemm<0><<<gblocks, 256, 0, stream>>>(buf1, wt3, buf0, N);
  k_agg<<<ablocks, 256, 0, stream>>>(buf0, dinv, row_ptr, csr, b3, buf1, N);

  int pblocks = (N + 127) / 128;  // 4 waves/block, 32 nodes/wave
  k_pool<<<pblocks, 256, 0, stream>>>(buf1, bv, pooled, N);
  k_final<<<B, 64, 0, stream>>>(pooled, lw, lb, out);
}